// Round 3
// baseline (625.527 us; speedup 1.0000x reference)
//
#include <hip/hip_runtime.h>

#define TOTAL_B 65536
#define NKR 1024   // K*RANK = 64*16
#define ZD 128

// ---------------------------------------------------------------------------
// Kernel 1: w = z @ W^T + b + 1e-6   (fp32)
// Round-3 restructure:
//  - NO transpose in staging: tiles stored [row][k] with row stride 36 floats
//    (9 float4; gcd(9,8)=1 spreads rows across all 8 bank-quads).
//    Staging = pure float4 copies, bank-balanced on write AND read
//    (write quad = (t>>3 + t&7) mod 8; read quad = (tx + k4) mod 8).
//    Kills the 1.26e7 4-way conflicts of the old scalar transpose writes.
//  - inner-product microkernel: acc[i][j] += dot4(zs[m_i][k4], ws[n_j][k4]),
//    m_i = ty+16i (wave: 4 distinct ty -> broadcast reads),
//    n_j = tx+16j (16 lanes stride-16 rows -> balanced quads).
//  - grid (512, 8): linear id = bx + 512*by, so the 8 n-blocks sharing one
//    z-slice have id mod 8 = bx mod 8 -> same XCD -> z fetched once from HBM.
// ---------------------------------------------------------------------------
__global__ __launch_bounds__(256) void gemm_zwt(
    const float* __restrict__ z, const float* __restrict__ W,
    const float* __restrict__ bias, float* __restrict__ out)
{
    __shared__ float zs[128][36];   // [row][k], 36-float stride (144 B)
    __shared__ float ws[128][36];

    const int tid = threadIdx.x;
    const int tx = tid & 15;        // n-lane
    const int ty = tid >> 4;        // m-lane
    const int m0 = blockIdx.x * 128;
    const int n0 = blockIdx.y * 128;

    float acc[8][8];
    #pragma unroll
    for (int i = 0; i < 8; ++i)
        #pragma unroll
        for (int j = 0; j < 8; ++j) acc[i][j] = 0.f;

    const int kq = (tid & 7) * 4;   // k-offset within 32-k tile (float4)
    const int mr = tid >> 3;        // row 0..31 within staging slice

    const float* gz = z + (size_t)(m0 + mr) * ZD + kq;
    const float* gw = W + (size_t)(n0 + mr) * ZD + kq;

    for (int kc = 0; kc < ZD; kc += 32) {
        // stage: straight float4 copies, no transpose
        #pragma unroll
        for (int p = 0; p < 4; ++p) {
            int row = mr + p * 32;
            float4 vz = *(const float4*)(gz + (size_t)p * 32 * ZD + kc);
            float4 vw = *(const float4*)(gw + (size_t)p * 32 * ZD + kc);
            *(float4*)&zs[row][kq] = vz;
            *(float4*)&ws[row][kq] = vw;
        }
        __syncthreads();

        #pragma unroll
        for (int k4 = 0; k4 < 8; ++k4) {
            float4 za[8];
            #pragma unroll
            for (int i = 0; i < 8; ++i)
                za[i] = *(const float4*)&zs[ty + 16 * i][k4 * 4];
            #pragma unroll
            for (int j = 0; j < 8; ++j) {
                float4 wa = *(const float4*)&ws[tx + 16 * j][k4 * 4];
                #pragma unroll
                for (int i = 0; i < 8; ++i) {
                    float s = acc[i][j];
                    s = fmaf(za[i].x, wa.x, s);
                    s = fmaf(za[i].y, wa.y, s);
                    s = fmaf(za[i].z, wa.z, s);
                    s = fmaf(za[i].w, wa.w, s);
                    acc[i][j] = s;
                }
            }
        }
        __syncthreads();
    }

    float bv[8];
    #pragma unroll
    for (int j = 0; j < 8; ++j) bv[j] = bias[n0 + tx + 16 * j] + 1e-6f;

    #pragma unroll
    for (int i = 0; i < 8; ++i) {
        size_t base = (size_t)(m0 + ty + 16 * i) * NKR + n0;
        #pragma unroll
        for (int j = 0; j < 8; ++j)
            out[base + tx + 16 * j] = acc[i][j] + bv[j];
    }
}

// ---------------------------------------------------------------------------
// Kernel 2: batched Householder QR, 16 lanes per matrix (4 matrices/wave),
// lane q holds rows {q, q+16, q+32, q+48}.  UNCHANGED from round 2 (passed,
// 305 -> <213 us): DPP rotation-butterfly reductions, rcp/sqrt builtins,
// descending in-place sorg2r, full-row stores.
// ---------------------------------------------------------------------------
template <int CTRL>
__device__ __forceinline__ float dpp_add(float v) {
    int x = __builtin_amdgcn_update_dpp(0, __float_as_int(v), CTRL, 0xF, 0xF, false);
    return v + __int_as_float(x);
}

__device__ __forceinline__ float rsum16(float v) {
    v = dpp_add<0x128>(v);   // row_ror:8
    v = dpp_add<0x124>(v);   // row_ror:4
    v = dpp_add<0x122>(v);   // row_ror:2
    v = dpp_add<0x121>(v);   // row_ror:1
    return v;
}

__global__ __launch_bounds__(256) void qr_batched(float* __restrict__ buf)
{
    const int tid = threadIdx.x;
    const int lq = tid & 15;                         // lane within 16-group
    const int item = (blockIdx.x * 256 + tid) >> 4;  // one matrix per group

    float* p = buf + (size_t)item * NKR + lq * 16;   // row lq, col 0

    // load: a[c][i] = A[lq + 16*i][c]
    float a[16][4];
    #pragma unroll
    for (int i = 0; i < 4; ++i) {
        #pragma unroll
        for (int cc = 0; cc < 16; cc += 4) {
            float4 v = *(const float4*)(p + i * 256 + cc);
            a[cc + 0][i] = v.x; a[cc + 1][i] = v.y;
            a[cc + 2][i] = v.z; a[cc + 3][i] = v.w;
        }
    }

    float tau[16];

    // ---- factorization (LAPACK sgeqr2 / slarfg convention) ----
    #pragma unroll
    for (int j = 0; j < 16; ++j) {
        float x0 = a[j][0], x1 = a[j][1], x2 = a[j][2], x3 = a[j][3];
        float x0m = (lq > j) ? x0 : 0.f;
        float pp = fmaf(x0m, x0m, fmaf(x1, x1, fmaf(x2, x2, x3 * x3)));
        float xn2   = rsum16(pp);
        float alpha = rsum16((lq == j) ? x0 : 0.f);

        float rr   = __builtin_amdgcn_sqrtf(fmaf(alpha, alpha, xn2));
        float beta = (alpha >= 0.f) ? -rr : rr;
        float dba  = beta - alpha;
        float tj   = dba * __builtin_amdgcn_rcpf(beta);
        float sc   = -__builtin_amdgcn_rcpf(dba);
        if (xn2 == 0.f) { tj = 0.f; sc = 0.f; }
        tau[j] = tj;

        float v0 = (lq == j) ? 1.f : ((lq > j) ? x0 * sc : 0.f);
        float v1 = x1 * sc, v2 = x2 * sc, v3 = x3 * sc;
        a[j][0] = v0; a[j][1] = v1; a[j][2] = v2; a[j][3] = v3;

        #pragma unroll
        for (int c = j + 1; c < 16; ++c) {
            float d = rsum16(fmaf(v0, a[c][0],
                        fmaf(v1, a[c][1],
                        fmaf(v2, a[c][2], v3 * a[c][3]))));
            float t = -tj * d;
            a[c][0] = fmaf(t, v0, a[c][0]);
            a[c][1] = fmaf(t, v1, a[c][1]);
            a[c][2] = fmaf(t, v2, a[c][2]);
            a[c][3] = fmaf(t, v3, a[c][3]);
        }
    }

    // ---- form Q (sorg2r, descending sweep, in place) ----
    #pragma unroll
    for (int j = 15; j >= 0; --j) {
        float tj = tau[j];
        float v0 = a[j][0], v1 = a[j][1], v2 = a[j][2], v3 = a[j][3];
        #pragma unroll
        for (int c = j + 1; c < 16; ++c) {
            float d = rsum16(fmaf(v0, a[c][0],
                        fmaf(v1, a[c][1],
                        fmaf(v2, a[c][2], v3 * a[c][3]))));
            float t = -tj * d;
            a[c][0] = fmaf(t, v0, a[c][0]);
            a[c][1] = fmaf(t, v1, a[c][1]);
            a[c][2] = fmaf(t, v2, a[c][2]);
            a[c][3] = fmaf(t, v3, a[c][3]);
        }
        float nt = -tj;
        a[j][0] = fmaf(nt, v0, (lq == j) ? 1.f : 0.f);
        a[j][1] = nt * v1;
        a[j][2] = nt * v2;
        a[j][3] = nt * v3;
    }

    // ---- store Q: full 64B rows; lanes 0..15 cover 16 consecutive rows ----
    #pragma unroll
    for (int i = 0; i < 4; ++i) {
        #pragma unroll
        for (int cc = 0; cc < 16; cc += 4) {
            float4 vv = {a[cc + 0][i], a[cc + 1][i], a[cc + 2][i], a[cc + 3][i]};
            *(float4*)(p + i * 256 + cc) = vv;
        }
    }
}

extern "C" void kernel_launch(void* const* d_in, const int* in_sizes, int n_in,
                              void* d_out, int out_size, void* d_ws, size_t ws_size,
                              hipStream_t stream) {
    const float* z = (const float*)d_in[0];
    const float* W = (const float*)d_in[1];
    const float* b = (const float*)d_in[2];
    float* out = (float*)d_out;

    dim3 ggrid(TOTAL_B / 128, NKR / 128);   // (512, 8): same-z blocks -> same XCD
    hipLaunchKernelGGL(gemm_zwt, ggrid, dim3(256), 0, stream, z, W, b, out);
    hipLaunchKernelGGL(qr_batched, dim3(TOTAL_B / 16), dim3(256), 0, stream, out);
}

// Round 4
// 567.039 us; speedup vs baseline: 1.1031x; 1.1031x over previous
//
#include <hip/hip_runtime.h>

#define TOTAL_B 65536
#define NKR 1024   // K*RANK = 64*16
#define ZD 128

// ---------------------------------------------------------------------------
// Kernel 1: w = z @ W^T + b + 1e-6   (fp32)
// Round-4 = round-2 structure (213 us proven) + two fixes:
//  - column-XOR swizzle col' = col ^ ((k>>2)&3)<<3 on the [k][row] tiles:
//    staging-write banks go from 4-way (16 banks) to 2-way (free, m136).
//    Thread-constant on writes (k>>2 == tid&7>>0 for its 4 k-rows),
//    loop-constant on reads; 16B alignment preserved.
//  - XCD swizzle: grid (8,512), xcd = bx (id mod 8), t = by. slice =
//    bx*64 + (t>>3), n = t&7: the 8 n-blocks of one z-slice run
//    consecutively on ONE XCD -> z-slice stays in that XCD's L2 (working
//    set ~1 MB z + 0.5 MB W << 4 MB); z fetched from HBM once.
// ---------------------------------------------------------------------------
__global__ __launch_bounds__(256) void gemm_zwt(
    const float* __restrict__ z, const float* __restrict__ W,
    const float* __restrict__ bias, float* __restrict__ out)
{
    __shared__ float zs[32][132];
    __shared__ float ws[32][132];

    const int tid = threadIdx.x;
    const int tx = tid & 15;
    const int ty = tid >> 4;

    // XCD-aware block remap (round-robin id mod 8 assumed, m157)
    const int xcd = blockIdx.x;          // 0..7  == linear_id & 7
    const int seq = blockIdx.y;          // 0..511 == linear_id >> 3
    const int m0 = (xcd * 64 + (seq >> 3)) * 128;   // z-slice
    const int n0 = (seq & 7) * 128;                 // n-block

    float acc[8][8];
    #pragma unroll
    for (int i = 0; i < 8; ++i)
        #pragma unroll
        for (int j = 0; j < 8; ++j) acc[i][j] = 0.f;

    const int kq = (tid & 7) * 4;   // k-offset within tile (float4 aligned)
    const int mr = tid >> 3;        // row 0..31 within 32-row staging slice
    const int xk = ((tid >> 2) & 2) << 2 | ((tid & 2) << 2);
    // xk = ((tid&7)>>2<<1 | ...) -- compute plainly below instead:
    const int xkw = (((kq >> 2) & 3) << 3);  // = ((tid&7)&3)<<3, write-side XOR

    const float* gz = z + (size_t)(m0 + mr) * ZD + kq;
    const float* gw = W + (size_t)(n0 + mr) * ZD + kq;

    // prefetch tile 0
    float4 vz[4], vw[4];
    #pragma unroll
    for (int p = 0; p < 4; ++p) {
        vz[p] = *(const float4*)(gz + (size_t)p * 32 * ZD);
        vw[p] = *(const float4*)(gw + (size_t)p * 32 * ZD);
    }

    #pragma unroll
    for (int kc = 0; kc < ZD; kc += 32) {
        // write staged tile (transpose to [k][row^xk])
        #pragma unroll
        for (int p = 0; p < 4; ++p) {
            int ml = (mr + p * 32) ^ xkw;
            zs[kq + 0][ml] = vz[p].x; zs[kq + 1][ml] = vz[p].y;
            zs[kq + 2][ml] = vz[p].z; zs[kq + 3][ml] = vz[p].w;
            ws[kq + 0][ml] = vw[p].x; ws[kq + 1][ml] = vw[p].y;
            ws[kq + 2][ml] = vw[p].z; ws[kq + 3][ml] = vw[p].w;
        }
        __syncthreads();

        // prefetch next tile into registers (hidden under compute below)
        if (kc + 32 < ZD) {
            #pragma unroll
            for (int p = 0; p < 4; ++p) {
                vz[p] = *(const float4*)(gz + (size_t)p * 32 * ZD + kc + 32);
                vw[p] = *(const float4*)(gw + (size_t)p * 32 * ZD + kc + 32);
            }
        }

        #pragma unroll 8
        for (int k = 0; k < 32; ++k) {
            const int xkr = ((k >> 2) & 3) << 3;   // compile-time per unrolled k
            float4 a0 = *(const float4*)&zs[k][(ty * 4) ^ xkr];
            float4 a1 = *(const float4*)&zs[k][64 + ((ty * 4) ^ xkr)];
            float4 c0 = *(const float4*)&ws[k][(tx * 4) ^ xkr];
            float4 c1 = *(const float4*)&ws[k][64 + ((tx * 4) ^ xkr)];
            float zr[8] = {a0.x, a0.y, a0.z, a0.w, a1.x, a1.y, a1.z, a1.w};
            float wr[8] = {c0.x, c0.y, c0.z, c0.w, c1.x, c1.y, c1.z, c1.w};
            #pragma unroll
            for (int i = 0; i < 8; ++i)
                #pragma unroll
                for (int j = 0; j < 8; ++j)
                    acc[i][j] = fmaf(zr[i], wr[j], acc[i][j]);
        }
        __syncthreads();
    }

    float bv0[4], bv1[4];
    #pragma unroll
    for (int j = 0; j < 4; ++j) {
        bv0[j] = bias[n0 + tx * 4 + j] + 1e-6f;
        bv1[j] = bias[n0 + 64 + tx * 4 + j] + 1e-6f;
    }

    #pragma unroll
    for (int i = 0; i < 8; ++i) {
        int row = (i < 4) ? (ty * 4 + i) : (64 + ty * 4 + i - 4);
        size_t base = (size_t)(m0 + row) * NKR + n0;
        float4 o0, o1;
        o0.x = acc[i][0] + bv0[0]; o0.y = acc[i][1] + bv0[1];
        o0.z = acc[i][2] + bv0[2]; o0.w = acc[i][3] + bv0[3];
        o1.x = acc[i][4] + bv1[0]; o1.y = acc[i][5] + bv1[1];
        o1.z = acc[i][6] + bv1[2]; o1.w = acc[i][7] + bv1[3];
        *(float4*)(out + base + tx * 4) = o0;
        *(float4*)(out + base + 64 + tx * 4) = o1;
    }
}

// ---------------------------------------------------------------------------
// Kernel 2: batched Householder QR, 16 lanes per matrix (4 matrices/wave),
// lane q holds rows {q, q+16, q+32, q+48}.
// Round-4: row-state as float2 ext-vectors so clang emits v_pk_fma_f32
// (VOP3P packed fp32) for the dot/apply bulk: ~halves VALU instruction
// count in the dominant loops and halves the dot chain depth. Pure codegen
// change -- no inline asm, no hazard risk. Summation order changes only.
// ---------------------------------------------------------------------------
typedef float f32x2 __attribute__((ext_vector_type(2)));

template <int CTRL>
__device__ __forceinline__ float dpp_add(float v) {
    int x = __builtin_amdgcn_update_dpp(0, __float_as_int(v), CTRL, 0xF, 0xF, false);
    return v + __int_as_float(x);
}

// allreduce-sum over each aligned 16-lane group; identical value on all 16
// lanes (rotation butterfly -> same combine order on every lane).
__device__ __forceinline__ float rsum16(float v) {
    v = dpp_add<0x128>(v);   // row_ror:8
    v = dpp_add<0x124>(v);   // row_ror:4
    v = dpp_add<0x122>(v);   // row_ror:2
    v = dpp_add<0x121>(v);   // row_ror:1
    return v;
}

__global__ __launch_bounds__(256) void qr_batched(float* __restrict__ buf)
{
    const int tid = threadIdx.x;
    const int lq = tid & 15;                         // lane within 16-group
    const int item = (blockIdx.x * 256 + tid) >> 4;  // one matrix per group

    float* p = buf + (size_t)item * NKR + lq * 16;   // row lq, col 0

    // a[c][h]: rows (lq+16*(2h)) in .x, (lq+16*(2h+1)) in .y, column c
    f32x2 a[16][2];
    #pragma unroll
    for (int i = 0; i < 4; ++i) {
        const int h = i >> 1;
        #pragma unroll
        for (int cc = 0; cc < 16; cc += 4) {
            float4 v = *(const float4*)(p + i * 256 + cc);
            if ((i & 1) == 0) {
                a[cc + 0][h].x = v.x; a[cc + 1][h].x = v.y;
                a[cc + 2][h].x = v.z; a[cc + 3][h].x = v.w;
            } else {
                a[cc + 0][h].y = v.x; a[cc + 1][h].y = v.y;
                a[cc + 2][h].y = v.z; a[cc + 3][h].y = v.w;
            }
        }
    }

    float tau[16];

    // ---- factorization (LAPACK sgeqr2 / slarfg convention) ----
    #pragma unroll
    for (int j = 0; j < 16; ++j) {
        f32x2 xlo = a[j][0], xhi = a[j][1];
        float x0 = xlo.x;
        f32x2 mlo = xlo;
        mlo.x = (lq > j) ? x0 : 0.f;   // row lq counts only when lq > j
        f32x2 pp2 = __builtin_elementwise_fma(mlo, mlo, xhi * xhi);
        float xn2   = rsum16(pp2.x + pp2.y);
        float alpha = rsum16((lq == j) ? x0 : 0.f);

        float rr   = __builtin_amdgcn_sqrtf(fmaf(alpha, alpha, xn2));
        float beta = (alpha >= 0.f) ? -rr : rr;
        float dba  = beta - alpha;
        float tj   = dba * __builtin_amdgcn_rcpf(beta);
        float sc   = -__builtin_amdgcn_rcpf(dba);
        if (xn2 == 0.f) { tj = 0.f; sc = 0.f; }
        tau[j] = tj;

        f32x2 v01, v23;
        v01.x = (lq == j) ? 1.f : ((lq > j) ? x0 * sc : 0.f);
        v01.y = xlo.y * sc;
        v23 = xhi * sc;
        a[j][0] = v01; a[j][1] = v23;

        #pragma unroll
        for (int c = j + 1; c < 16; ++c) {
            f32x2 d2 = __builtin_elementwise_fma(v01, a[c][0], v23 * a[c][1]);
            float d = rsum16(d2.x + d2.y);
            float t = -tj * d;
            f32x2 t2 = {t, t};
            a[c][0] = __builtin_elementwise_fma(t2, v01, a[c][0]);
            a[c][1] = __builtin_elementwise_fma(t2, v23, a[c][1]);
        }
    }

    // ---- form Q (sorg2r, descending sweep, in place) ----
    #pragma unroll
    for (int j = 15; j >= 0; --j) {
        float tj = tau[j];
        f32x2 v01 = a[j][0], v23 = a[j][1];
        #pragma unroll
        for (int c = j + 1; c < 16; ++c) {
            f32x2 d2 = __builtin_elementwise_fma(v01, a[c][0], v23 * a[c][1]);
            float d = rsum16(d2.x + d2.y);
            float t = -tj * d;
            f32x2 t2 = {t, t};
            a[c][0] = __builtin_elementwise_fma(t2, v01, a[c][0]);
            a[c][1] = __builtin_elementwise_fma(t2, v23, a[c][1]);
        }
        float nt = -tj;
        f32x2 nt2 = {nt, nt};
        f32x2 e0 = {(lq == j) ? 1.f : 0.f, 0.f};
        a[j][0] = __builtin_elementwise_fma(nt2, v01, e0);
        a[j][1] = v23 * nt;
    }

    // ---- store Q: full 64B rows; lanes 0..15 cover 16 consecutive rows ----
    #pragma unroll
    for (int i = 0; i < 4; ++i) {
        const int h = i >> 1;
        #pragma unroll
        for (int cc = 0; cc < 16; cc += 4) {
            float4 vv;
            if ((i & 1) == 0) {
                vv.x = a[cc + 0][h].x; vv.y = a[cc + 1][h].x;
                vv.z = a[cc + 2][h].x; vv.w = a[cc + 3][h].x;
            } else {
                vv.x = a[cc + 0][h].y; vv.y = a[cc + 1][h].y;
                vv.z = a[cc + 2][h].y; vv.w = a[cc + 3][h].y;
            }
            *(float4*)(p + i * 256 + cc) = vv;
        }
    }
}

extern "C" void kernel_launch(void* const* d_in, const int* in_sizes, int n_in,
                              void* d_out, int out_size, void* d_ws, size_t ws_size,
                              hipStream_t stream) {
    const float* z = (const float*)d_in[0];
    const float* W = (const float*)d_in[1];
    const float* b = (const float*)d_in[2];
    float* out = (float*)d_out;

    dim3 ggrid(8, 512);   // bx = XCD lane (id&7), by = sequence on that XCD
    hipLaunchKernelGGL(gemm_zwt, ggrid, dim3(256), 0, stream, z, W, b, out);
    hipLaunchKernelGGL(qr_batched, dim3(TOTAL_B / 16), dim3(256), 0, stream, out);
}